// Round 1
// baseline (1563.388 us; speedup 1.0000x reference)
//
#include <hip/hip_runtime.h>
#include <math.h>

// ---------------------------------------------------------------------------
// 2-layer graph conv (1-wide features):
//   layer: agg[v] = sum_{(u->v)} x[u];  x = relu(agg * w[i])
//   out   = sigmoid(x + bias)
// ---------------------------------------------------------------------------

__global__ void scatter_add4(const float* __restrict__ x,
                             const int* __restrict__ src,
                             const int* __restrict__ dst,
                             float* __restrict__ agg,
                             int nE4, int nE) {
    int tid = blockIdx.x * blockDim.x + threadIdx.x;
    int stride = gridDim.x * blockDim.x;
    for (int i = tid; i < nE4; i += stride) {
        int4 s = reinterpret_cast<const int4*>(src)[i];
        int4 d = reinterpret_cast<const int4*>(dst)[i];
        atomicAdd(&agg[d.x], x[s.x]);
        atomicAdd(&agg[d.y], x[s.y]);
        atomicAdd(&agg[d.z], x[s.z]);
        atomicAdd(&agg[d.w], x[s.w]);
    }
    // tail (nE not divisible by 4) — handled by the first few threads
    int tail_start = nE4 * 4;
    int e = tail_start + tid;
    if (e < nE) {
        atomicAdd(&agg[dst[e]], x[src[e]]);
    }
}

// x = relu(x * w), in place, float4-vectorized
__global__ void relu_scale4(float* __restrict__ a,
                            const float* __restrict__ w,
                            int n4) {
    float wv = w[0];
    int tid = blockIdx.x * blockDim.x + threadIdx.x;
    int stride = gridDim.x * blockDim.x;
    for (int i = tid; i < n4; i += stride) {
        float4 v = reinterpret_cast<float4*>(a)[i];
        v.x = fmaxf(v.x * wv, 0.0f);
        v.y = fmaxf(v.y * wv, 0.0f);
        v.z = fmaxf(v.z * wv, 0.0f);
        v.w = fmaxf(v.w * wv, 0.0f);
        reinterpret_cast<float4*>(a)[i] = v;
    }
}

// out = sigmoid(relu(out * w) + bias), in place, float4-vectorized
__global__ void finish4(float* __restrict__ o,
                        const float* __restrict__ w,
                        const float* __restrict__ bias,
                        int n4) {
    float wv = w[0];
    float b = bias[0];
    int tid = blockIdx.x * blockDim.x + threadIdx.x;
    int stride = gridDim.x * blockDim.x;
    for (int i = tid; i < n4; i += stride) {
        float4 v = reinterpret_cast<float4*>(o)[i];
        float sx = fmaxf(v.x * wv, 0.0f) + b;
        float sy = fmaxf(v.y * wv, 0.0f) + b;
        float sz = fmaxf(v.z * wv, 0.0f) + b;
        float sw = fmaxf(v.w * wv, 0.0f) + b;
        v.x = 1.0f / (1.0f + __expf(-sx));
        v.y = 1.0f / (1.0f + __expf(-sy));
        v.z = 1.0f / (1.0f + __expf(-sz));
        v.w = 1.0f / (1.0f + __expf(-sw));
        reinterpret_cast<float4*>(o)[i] = v;
    }
}

extern "C" void kernel_launch(void* const* d_in, const int* in_sizes, int n_in,
                              void* d_out, int out_size, void* d_ws, size_t ws_size,
                              hipStream_t stream) {
    const float* x    = (const float*)d_in[0];            // [N] node features
    const int*   ei   = (const int*)d_in[1];              // [2, nE] edge index (int32 per harness)
    const float* w    = (const float*)d_in[2];            // [2] layer weights (1x1 each)
    const float* bias = (const float*)d_in[3];            // scalar

    int n  = in_sizes[0];
    int nE = in_sizes[1] / 2;
    const int* src = ei;
    const int* dst = ei + nE;

    float* agg1 = (float*)d_ws;      // layer-1 accumulator (4 MB)
    float* out  = (float*)d_out;     // layer-2 accumulator, then final output

    // zero the accumulators (ws/out are poisoned 0xAA and never re-poisoned)
    hipMemsetAsync(agg1, 0, (size_t)n * sizeof(float), stream);
    hipMemsetAsync(out,  0, (size_t)n * sizeof(float), stream);

    int nE4 = nE / 4;
    dim3 blk(256);
    int eblocks = (nE4 + 255) / 256;
    if (eblocks > 4096) eblocks = 4096;
    int n4 = n / 4;
    int nblocks = (n4 + 255) / 256;
    if (nblocks > 2048) nblocks = 2048;

    // layer 1: agg1 = scatter_add(x);  agg1 = relu(agg1 * w0)
    scatter_add4<<<eblocks, blk, 0, stream>>>(x, src, dst, agg1, nE4, nE);
    relu_scale4<<<nblocks, blk, 0, stream>>>(agg1, w + 0, n4);

    // layer 2: out = scatter_add(agg1);  out = sigmoid(relu(out * w1) + bias)
    scatter_add4<<<eblocks, blk, 0, stream>>>(agg1, src, dst, out, nE4, nE);
    finish4<<<nblocks, blk, 0, stream>>>(out, w + 1, bias, n4);
}

// Round 2
// 434.723 us; speedup vs baseline: 3.5963x; 3.5963x over previous
//
#include <hip/hip_runtime.h>
#include <math.h>

// ---------------------------------------------------------------------------
// 2-layer graph conv (1-wide features), atomic-free via dst-binned counting
// sort (done once, reused by both layers) + per-bin LDS accumulation.
//   layer: agg[v] = sum_{(u->v)} x[u];  x = relu(agg * w[i])
//   out   = sigmoid(x + bias)
// Packing: N <= 2^20, BINSZ=2048 -> entry = (dst_low11 << 20) | src20 (31 bits)
// ---------------------------------------------------------------------------

#define BINSHIFT 11
#define BINSZ    2048
#define MAXNB    512
#define CHUNK    8192

// ========================= new binned path =========================

// A1: per-bin edge counts (LDS histogram, one global atomic per block per bin)
__global__ void count_bins(const int* __restrict__ dst, int nE, int NB,
                           int* __restrict__ counts) {
    __shared__ int h[MAXNB];
    for (int t = threadIdx.x; t < NB; t += blockDim.x) h[t] = 0;
    __syncthreads();
    int tid = blockIdx.x * blockDim.x + threadIdx.x;
    int stride = gridDim.x * blockDim.x;
    int nE4 = nE >> 2;
    for (int i = tid; i < nE4; i += stride) {
        int4 d = reinterpret_cast<const int4*>(dst)[i];
        atomicAdd(&h[d.x >> BINSHIFT], 1);
        atomicAdd(&h[d.y >> BINSHIFT], 1);
        atomicAdd(&h[d.z >> BINSHIFT], 1);
        atomicAdd(&h[d.w >> BINSHIFT], 1);
    }
    for (int e = (nE4 << 2) + tid; e < nE; e += stride)
        atomicAdd(&h[dst[e] >> BINSHIFT], 1);
    __syncthreads();
    for (int t = threadIdx.x; t < NB; t += blockDim.x)
        if (h[t]) atomicAdd(&counts[t], h[t]);
}

// A2: exclusive scan of NB (<=512) counts -> offsets[NB+1], cursors
__global__ void scan_bins(const int* __restrict__ counts, int* __restrict__ offsets,
                          int* __restrict__ cursors, int NB) {
    __shared__ int s[MAXNB];
    int t = threadIdx.x;
    int c = (t < NB) ? counts[t] : 0;
    s[t] = c;
    __syncthreads();
    for (int off = 1; off < MAXNB; off <<= 1) {
        int v = (t >= off) ? s[t - off] : 0;
        __syncthreads();
        s[t] += v;
        __syncthreads();
    }
    if (t < NB) {
        int excl = s[t] - c;
        offsets[t] = excl;
        cursors[t] = excl;
        if (t == NB - 1) offsets[NB] = s[t];
    }
}

// A3: scatter packed edges into bin regions. One chunk of CHUNK edges / block.
__global__ void scatter_bins(const int* __restrict__ src, const int* __restrict__ dst,
                             int nE, int NB, int* __restrict__ cursors,
                             unsigned int* __restrict__ binned) {
    __shared__ int cnt[MAXNB];
    __shared__ int base[MAXNB];
    int cb = blockIdx.x * CHUNK;
    int nHere = nE - cb;
    if (nHere > CHUNK) nHere = CHUNK;
    for (int t = threadIdx.x; t < NB; t += blockDim.x) cnt[t] = 0;
    __syncthreads();

    // pass 1: count this chunk's bins (dst only)
    if (nHere == CHUNK) {
        const int4* d4 = reinterpret_cast<const int4*>(dst + cb);
        #pragma unroll
        for (int k = 0; k < CHUNK / 1024; ++k) {
            int4 d = d4[k * 256 + threadIdx.x];
            atomicAdd(&cnt[d.x >> BINSHIFT], 1);
            atomicAdd(&cnt[d.y >> BINSHIFT], 1);
            atomicAdd(&cnt[d.z >> BINSHIFT], 1);
            atomicAdd(&cnt[d.w >> BINSHIFT], 1);
        }
    } else {
        for (int j = threadIdx.x; j < nHere; j += blockDim.x)
            atomicAdd(&cnt[dst[cb + j] >> BINSHIFT], 1);
    }
    __syncthreads();

    // reserve space per bin
    for (int t = threadIdx.x; t < NB; t += blockDim.x) {
        int c = cnt[t];
        base[t] = c ? atomicAdd(&cursors[t], c) : 0;
    }
    __syncthreads();
    for (int t = threadIdx.x; t < NB; t += blockDim.x) cnt[t] = 0;
    __syncthreads();

    // pass 2: rank within chunk, write packed entries (dst re-read is L2-hot)
    if (nHere == CHUNK) {
        const int4* d4 = reinterpret_cast<const int4*>(dst + cb);
        const int4* s4 = reinterpret_cast<const int4*>(src + cb);
        #pragma unroll
        for (int k = 0; k < CHUNK / 1024; ++k) {
            int4 d = d4[k * 256 + threadIdx.x];
            int4 s = s4[k * 256 + threadIdx.x];
            int b, r;
            b = d.x >> BINSHIFT; r = atomicAdd(&cnt[b], 1);
            binned[base[b] + r] = ((unsigned)(d.x & (BINSZ - 1)) << 20) | (unsigned)s.x;
            b = d.y >> BINSHIFT; r = atomicAdd(&cnt[b], 1);
            binned[base[b] + r] = ((unsigned)(d.y & (BINSZ - 1)) << 20) | (unsigned)s.y;
            b = d.z >> BINSHIFT; r = atomicAdd(&cnt[b], 1);
            binned[base[b] + r] = ((unsigned)(d.z & (BINSZ - 1)) << 20) | (unsigned)s.z;
            b = d.w >> BINSHIFT; r = atomicAdd(&cnt[b], 1);
            binned[base[b] + r] = ((unsigned)(d.w & (BINSZ - 1)) << 20) | (unsigned)s.w;
        }
    } else {
        for (int j = threadIdx.x; j < nHere; j += blockDim.x) {
            int dv = dst[cb + j];
            int sv = src[cb + j];
            int b = dv >> BINSHIFT;
            int r = atomicAdd(&cnt[b], 1);
            binned[base[b] + r] = ((unsigned)(dv & (BINSZ - 1)) << 20) | (unsigned)sv;
        }
    }
}

// B: per-bin gather + LDS accumulate + fused epilogue. One block per bin.
template <int FINAL>
__global__ void reduce_bins(const unsigned int* __restrict__ binned,
                            const int* __restrict__ offsets,
                            const float* __restrict__ xin,
                            const float* __restrict__ wp,
                            const float* __restrict__ bp,
                            float* __restrict__ xout, int n) {
    __shared__ float acc[BINSZ];
    int b = blockIdx.x;
    for (int t = threadIdx.x; t < BINSZ; t += blockDim.x) acc[t] = 0.f;
    __syncthreads();
    int start = offsets[b];
    int end = offsets[b + 1];
    int nth = blockDim.x;
    int i = start + threadIdx.x;
    for (; i + 3 * nth < end; i += 4 * nth) {
        unsigned p0 = binned[i];
        unsigned p1 = binned[i + nth];
        unsigned p2 = binned[i + 2 * nth];
        unsigned p3 = binned[i + 3 * nth];
        float v0 = xin[p0 & 0xFFFFFu];
        float v1 = xin[p1 & 0xFFFFFu];
        float v2 = xin[p2 & 0xFFFFFu];
        float v3 = xin[p3 & 0xFFFFFu];
        atomicAdd(&acc[p0 >> 20], v0);
        atomicAdd(&acc[p1 >> 20], v1);
        atomicAdd(&acc[p2 >> 20], v2);
        atomicAdd(&acc[p3 >> 20], v3);
    }
    for (; i < end; i += nth) {
        unsigned p = binned[i];
        atomicAdd(&acc[p >> 20], xin[p & 0xFFFFFu]);
    }
    __syncthreads();
    float w = wp[0];
    float bias = FINAL ? bp[0] : 0.f;
    int nodeBase = b << BINSHIFT;
    for (int t = threadIdx.x; t < BINSZ; t += blockDim.x) {
        int node = nodeBase + t;
        if (node < n) {
            float h = fmaxf(acc[t] * w, 0.f);
            if (FINAL) h = 1.f / (1.f + __expf(-(h + bias)));
            xout[node] = h;
        }
    }
}

// ========================= fallback (round-1) path =========================

__global__ void scatter_add4(const float* __restrict__ x,
                             const int* __restrict__ src,
                             const int* __restrict__ dst,
                             float* __restrict__ agg,
                             int nE4, int nE) {
    int tid = blockIdx.x * blockDim.x + threadIdx.x;
    int stride = gridDim.x * blockDim.x;
    for (int i = tid; i < nE4; i += stride) {
        int4 s = reinterpret_cast<const int4*>(src)[i];
        int4 d = reinterpret_cast<const int4*>(dst)[i];
        atomicAdd(&agg[d.x], x[s.x]);
        atomicAdd(&agg[d.y], x[s.y]);
        atomicAdd(&agg[d.z], x[s.z]);
        atomicAdd(&agg[d.w], x[s.w]);
    }
    int e = nE4 * 4 + tid;
    if (e < nE) atomicAdd(&agg[dst[e]], x[src[e]]);
}

__global__ void relu_scale4(float* __restrict__ a, const float* __restrict__ w, int n4) {
    float wv = w[0];
    int tid = blockIdx.x * blockDim.x + threadIdx.x;
    int stride = gridDim.x * blockDim.x;
    for (int i = tid; i < n4; i += stride) {
        float4 v = reinterpret_cast<float4*>(a)[i];
        v.x = fmaxf(v.x * wv, 0.0f);
        v.y = fmaxf(v.y * wv, 0.0f);
        v.z = fmaxf(v.z * wv, 0.0f);
        v.w = fmaxf(v.w * wv, 0.0f);
        reinterpret_cast<float4*>(a)[i] = v;
    }
}

__global__ void finish4(float* __restrict__ o, const float* __restrict__ w,
                        const float* __restrict__ bias, int n4) {
    float wv = w[0];
    float b = bias[0];
    int tid = blockIdx.x * blockDim.x + threadIdx.x;
    int stride = gridDim.x * blockDim.x;
    for (int i = tid; i < n4; i += stride) {
        float4 v = reinterpret_cast<float4*>(o)[i];
        float sx = fmaxf(v.x * wv, 0.0f) + b;
        float sy = fmaxf(v.y * wv, 0.0f) + b;
        float sz = fmaxf(v.z * wv, 0.0f) + b;
        float sw = fmaxf(v.w * wv, 0.0f) + b;
        v.x = 1.0f / (1.0f + __expf(-sx));
        v.y = 1.0f / (1.0f + __expf(-sy));
        v.z = 1.0f / (1.0f + __expf(-sz));
        v.w = 1.0f / (1.0f + __expf(-sw));
        reinterpret_cast<float4*>(o)[i] = v;
    }
}

// ========================= launcher =========================

extern "C" void kernel_launch(void* const* d_in, const int* in_sizes, int n_in,
                              void* d_out, int out_size, void* d_ws, size_t ws_size,
                              hipStream_t stream) {
    const float* x    = (const float*)d_in[0];
    const int*   ei   = (const int*)d_in[1];
    const float* w    = (const float*)d_in[2];
    const float* bias = (const float*)d_in[3];

    int n  = in_sizes[0];
    int nE = in_sizes[1] / 2;
    const int* src = ei;
    const int* dst = ei + nE;
    float* out = (float*)d_out;

    int NB = (n + BINSZ - 1) >> BINSHIFT;

    // ws layout: binned[nE] | counts[512] | offsets[513] | cursors[512] | h1[n]
    size_t sz_binned = ((size_t)nE * 4 + 255) & ~(size_t)255;
    size_t sz_meta   = ((size_t)(MAXNB * 2 + MAXNB + 1) * 4 + 255) & ~(size_t)255;
    size_t sz_h1     = ((size_t)n * 4 + 255) & ~(size_t)255;
    size_t need      = sz_binned + sz_meta + sz_h1;

    bool can_bin = (n <= (1 << 20)) && (NB <= MAXNB) && (ws_size >= need);

    if (can_bin) {
        unsigned int* binned = (unsigned int*)d_ws;
        int* counts  = (int*)((char*)d_ws + sz_binned);
        int* offsets = counts + MAXNB;
        int* cursors = offsets + MAXNB + 1;
        float* h1    = (float*)((char*)d_ws + sz_binned + sz_meta);

        hipMemsetAsync(counts, 0, MAXNB * sizeof(int), stream);

        dim3 blk256(256), blk512(512);
        count_bins<<<2048, blk256, 0, stream>>>(dst, nE, NB, counts);
        scan_bins<<<1, MAXNB, 0, stream>>>(counts, offsets, cursors, NB);
        int nChunks = (nE + CHUNK - 1) / CHUNK;
        scatter_bins<<<nChunks, blk256, 0, stream>>>(src, dst, nE, NB, cursors, binned);

        reduce_bins<0><<<NB, blk512, 0, stream>>>(binned, offsets, x, w + 0, bias, h1, n);
        reduce_bins<1><<<NB, blk512, 0, stream>>>(binned, offsets, h1, w + 1, bias, out, n);
    } else {
        float* agg1 = (float*)d_ws;
        hipMemsetAsync(agg1, 0, (size_t)n * sizeof(float), stream);
        hipMemsetAsync(out,  0, (size_t)n * sizeof(float), stream);
        int nE4 = nE / 4;
        dim3 blk(256);
        int eblocks = (nE4 + 255) / 256; if (eblocks > 4096) eblocks = 4096;
        int n4 = n / 4;
        int nblocks = (n4 + 255) / 256; if (nblocks > 2048) nblocks = 2048;
        scatter_add4<<<eblocks, blk, 0, stream>>>(x, src, dst, agg1, nE4, nE);
        relu_scale4<<<nblocks, blk, 0, stream>>>(agg1, w + 0, n4);
        scatter_add4<<<eblocks, blk, 0, stream>>>(agg1, src, dst, out, nE4, nE);
        finish4<<<nblocks, blk, 0, stream>>>(out, w + 1, bias, n4);
    }
}

// Round 3
// 316.289 us; speedup vs baseline: 4.9429x; 1.3744x over previous
//
#include <hip/hip_runtime.h>
#include <math.h>

// ---------------------------------------------------------------------------
// 2-layer graph conv (1-wide features), atomic-free via dst-binned counting
// sort (done once, reused by both layers) + per-bin LDS accumulation.
//   layer: agg[v] = sum_{(u->v)} x[u];  x = relu(agg * w[i])
//   out   = sigmoid(x + bias)
// Packing: N <= 2^20, BINSZ=2048 -> entry = (dst_low11 << 20) | src20 (31 bits)
// R3: scatter_staged — LDS-staged bin scatter with coalesced global writes
//     (R2's scatter_bins had 5.5x write amplification: 354MB for 64MB data)
// ---------------------------------------------------------------------------

#define BINSHIFT 11
#define BINSZ    2048
#define MAXNB    512
#define SCHUNK   16384
#define STHREADS 512

// A1: per-bin edge counts (LDS histogram, one global atomic per block per bin)
__global__ void count_bins(const int* __restrict__ dst, int nE, int NB,
                           int* __restrict__ counts) {
    __shared__ int h[MAXNB];
    for (int t = threadIdx.x; t < MAXNB; t += blockDim.x) h[t] = 0;
    __syncthreads();
    int tid = blockIdx.x * blockDim.x + threadIdx.x;
    int stride = gridDim.x * blockDim.x;
    int nE4 = nE >> 2;
    for (int i = tid; i < nE4; i += stride) {
        int4 d = reinterpret_cast<const int4*>(dst)[i];
        atomicAdd(&h[d.x >> BINSHIFT], 1);
        atomicAdd(&h[d.y >> BINSHIFT], 1);
        atomicAdd(&h[d.z >> BINSHIFT], 1);
        atomicAdd(&h[d.w >> BINSHIFT], 1);
    }
    for (int e = (nE4 << 2) + tid; e < nE; e += stride)
        atomicAdd(&h[dst[e] >> BINSHIFT], 1);
    __syncthreads();
    for (int t = threadIdx.x; t < NB; t += blockDim.x)
        if (h[t]) atomicAdd(&counts[t], h[t]);
}

// A2: exclusive scan of NB (<=512) counts -> offsets[NB+1], cursors
__global__ void scan_bins(const int* __restrict__ counts, int* __restrict__ offsets,
                          int* __restrict__ cursors, int NB) {
    __shared__ int s[MAXNB];
    int t = threadIdx.x;
    int c = (t < NB) ? counts[t] : 0;
    s[t] = c;
    __syncthreads();
    for (int off = 1; off < MAXNB; off <<= 1) {
        int v = (t >= off) ? s[t - off] : 0;
        __syncthreads();
        s[t] += v;
        __syncthreads();
    }
    if (t < NB) {
        int excl = s[t] - c;
        offsets[t] = excl;
        cursors[t] = excl;
        if (t == NB - 1) offsets[NB] = s[t];
    }
}

// A3: LDS-staged scatter. One block per SCHUNK-edge chunk, 512 threads.
// Stages packed entries bin-ordered in LDS, then waves copy whole bin
// segments to global => fully coalesced writes.
__global__ __launch_bounds__(STHREADS, 2)
void scatter_staged(const int* __restrict__ src, const int* __restrict__ dst,
                    int nE, int NB, int* __restrict__ cursors,
                    unsigned int* __restrict__ binned) {
    __shared__ unsigned int stage[SCHUNK];
    __shared__ int cnt[MAXNB];
    __shared__ int lstart[MAXNB];   // exclusive local start per bin
    __shared__ int lscan[MAXNB];
    __shared__ int delta[MAXNB];    // global_base - local_start

    int t = threadIdx.x;
    int cb = blockIdx.x * SCHUNK;
    int nHere = nE - cb;
    if (nHere > SCHUNK) nHere = SCHUNK;

    cnt[t] = 0;                      // STHREADS == MAXNB == 512
    __syncthreads();

    // ---- pass 1: count this chunk's bins ----
    if (nHere == SCHUNK) {
        const int4* d4 = reinterpret_cast<const int4*>(dst + cb);
        #pragma unroll
        for (int k = 0; k < SCHUNK / 4 / STHREADS; ++k) {   // 8 iters
            int4 d = d4[k * STHREADS + t];
            atomicAdd(&cnt[d.x >> BINSHIFT], 1);
            atomicAdd(&cnt[d.y >> BINSHIFT], 1);
            atomicAdd(&cnt[d.z >> BINSHIFT], 1);
            atomicAdd(&cnt[d.w >> BINSHIFT], 1);
        }
    } else {
        for (int j = t; j < nHere; j += STHREADS)
            atomicAdd(&cnt[dst[cb + j] >> BINSHIFT], 1);
    }
    __syncthreads();

    // ---- in-block scan (Hillis-Steele over 512) ----
    int c = cnt[t];
    lscan[t] = c;
    __syncthreads();
    for (int off = 1; off < MAXNB; off <<= 1) {
        int v = (t >= off) ? lscan[t - off] : 0;
        __syncthreads();
        lscan[t] += v;
        __syncthreads();
    }
    lstart[t] = lscan[t] - c;        // exclusive

    // ---- reserve global space, one atomic per non-empty bin ----
    int gb = 0;
    if (t < NB && c) gb = atomicAdd(&cursors[t], c);
    delta[t] = gb - lstart[t];
    cnt[t] = 0;
    __syncthreads();

    // ---- pass 2: rank + stage (bin-ordered in LDS) ----
    if (nHere == SCHUNK) {
        const int4* d4 = reinterpret_cast<const int4*>(dst + cb);
        const int4* s4 = reinterpret_cast<const int4*>(src + cb);
        #pragma unroll
        for (int k = 0; k < SCHUNK / 4 / STHREADS; ++k) {
            int4 d = d4[k * STHREADS + t];
            int4 s = s4[k * STHREADS + t];
            int b, r;
            b = d.x >> BINSHIFT; r = atomicAdd(&cnt[b], 1);
            stage[lstart[b] + r] = ((unsigned)(d.x & (BINSZ - 1)) << 20) | (unsigned)s.x;
            b = d.y >> BINSHIFT; r = atomicAdd(&cnt[b], 1);
            stage[lstart[b] + r] = ((unsigned)(d.y & (BINSZ - 1)) << 20) | (unsigned)s.y;
            b = d.z >> BINSHIFT; r = atomicAdd(&cnt[b], 1);
            stage[lstart[b] + r] = ((unsigned)(d.z & (BINSZ - 1)) << 20) | (unsigned)s.z;
            b = d.w >> BINSHIFT; r = atomicAdd(&cnt[b], 1);
            stage[lstart[b] + r] = ((unsigned)(d.w & (BINSZ - 1)) << 20) | (unsigned)s.w;
        }
    } else {
        for (int j = t; j < nHere; j += STHREADS) {
            int dv = dst[cb + j];
            int sv = src[cb + j];
            int b = dv >> BINSHIFT;
            int r = atomicAdd(&cnt[b], 1);
            stage[lstart[b] + r] = ((unsigned)(dv & (BINSZ - 1)) << 20) | (unsigned)sv;
        }
    }
    __syncthreads();

    // ---- output: one wave per bin, coalesced segment copy ----
    int wave = t >> 6, lane = t & 63;
    for (int b = wave; b < NB; b += STHREADS / 64) {
        int s0 = lstart[b];
        int s1 = s0 + cnt[b];
        int dlt = delta[b];
        for (int j = s0 + lane; j < s1; j += 64)
            binned[dlt + j] = stage[j];
    }
}

// B: per-bin gather + LDS accumulate + fused epilogue. One block per bin.
template <int FINAL>
__global__ void reduce_bins(const unsigned int* __restrict__ binned,
                            const int* __restrict__ offsets,
                            const float* __restrict__ xin,
                            const float* __restrict__ wp,
                            const float* __restrict__ bp,
                            float* __restrict__ xout, int n) {
    __shared__ float acc[BINSZ];
    int b = blockIdx.x;
    for (int t = threadIdx.x; t < BINSZ; t += blockDim.x) acc[t] = 0.f;
    __syncthreads();
    int start = offsets[b];
    int end = offsets[b + 1];
    int nth = blockDim.x;
    int i = start + threadIdx.x;
    for (; i + 3 * nth < end; i += 4 * nth) {
        unsigned p0 = binned[i];
        unsigned p1 = binned[i + nth];
        unsigned p2 = binned[i + 2 * nth];
        unsigned p3 = binned[i + 3 * nth];
        float v0 = xin[p0 & 0xFFFFFu];
        float v1 = xin[p1 & 0xFFFFFu];
        float v2 = xin[p2 & 0xFFFFFu];
        float v3 = xin[p3 & 0xFFFFFu];
        atomicAdd(&acc[p0 >> 20], v0);
        atomicAdd(&acc[p1 >> 20], v1);
        atomicAdd(&acc[p2 >> 20], v2);
        atomicAdd(&acc[p3 >> 20], v3);
    }
    for (; i < end; i += nth) {
        unsigned p = binned[i];
        atomicAdd(&acc[p >> 20], xin[p & 0xFFFFFu]);
    }
    __syncthreads();
    float w = wp[0];
    float bias = FINAL ? bp[0] : 0.f;
    int nodeBase = b << BINSHIFT;
    for (int t = threadIdx.x; t < BINSZ; t += blockDim.x) {
        int node = nodeBase + t;
        if (node < n) {
            float h = fmaxf(acc[t] * w, 0.f);
            if (FINAL) h = 1.f / (1.f + __expf(-(h + bias)));
            xout[node] = h;
        }
    }
}

// ========================= fallback (round-1) path =========================

__global__ void scatter_add4(const float* __restrict__ x,
                             const int* __restrict__ src,
                             const int* __restrict__ dst,
                             float* __restrict__ agg,
                             int nE4, int nE) {
    int tid = blockIdx.x * blockDim.x + threadIdx.x;
    int stride = gridDim.x * blockDim.x;
    for (int i = tid; i < nE4; i += stride) {
        int4 s = reinterpret_cast<const int4*>(src)[i];
        int4 d = reinterpret_cast<const int4*>(dst)[i];
        atomicAdd(&agg[d.x], x[s.x]);
        atomicAdd(&agg[d.y], x[s.y]);
        atomicAdd(&agg[d.z], x[s.z]);
        atomicAdd(&agg[d.w], x[s.w]);
    }
    int e = nE4 * 4 + tid;
    if (e < nE) atomicAdd(&agg[dst[e]], x[src[e]]);
}

__global__ void relu_scale4(float* __restrict__ a, const float* __restrict__ w, int n4) {
    float wv = w[0];
    int tid = blockIdx.x * blockDim.x + threadIdx.x;
    int stride = gridDim.x * blockDim.x;
    for (int i = tid; i < n4; i += stride) {
        float4 v = reinterpret_cast<float4*>(a)[i];
        v.x = fmaxf(v.x * wv, 0.0f);
        v.y = fmaxf(v.y * wv, 0.0f);
        v.z = fmaxf(v.z * wv, 0.0f);
        v.w = fmaxf(v.w * wv, 0.0f);
        reinterpret_cast<float4*>(a)[i] = v;
    }
}

__global__ void finish4(float* __restrict__ o, const float* __restrict__ w,
                        const float* __restrict__ bias, int n4) {
    float wv = w[0];
    float b = bias[0];
    int tid = blockIdx.x * blockDim.x + threadIdx.x;
    int stride = gridDim.x * blockDim.x;
    for (int i = tid; i < n4; i += stride) {
        float4 v = reinterpret_cast<float4*>(o)[i];
        float sx = fmaxf(v.x * wv, 0.0f) + b;
        float sy = fmaxf(v.y * wv, 0.0f) + b;
        float sz = fmaxf(v.z * wv, 0.0f) + b;
        float sw = fmaxf(v.w * wv, 0.0f) + b;
        v.x = 1.0f / (1.0f + __expf(-sx));
        v.y = 1.0f / (1.0f + __expf(-sy));
        v.z = 1.0f / (1.0f + __expf(-sz));
        v.w = 1.0f / (1.0f + __expf(-sw));
        reinterpret_cast<float4*>(o)[i] = v;
    }
}

// ========================= launcher =========================

extern "C" void kernel_launch(void* const* d_in, const int* in_sizes, int n_in,
                              void* d_out, int out_size, void* d_ws, size_t ws_size,
                              hipStream_t stream) {
    const float* x    = (const float*)d_in[0];
    const int*   ei   = (const int*)d_in[1];
    const float* w    = (const float*)d_in[2];
    const float* bias = (const float*)d_in[3];

    int n  = in_sizes[0];
    int nE = in_sizes[1] / 2;
    const int* src = ei;
    const int* dst = ei + nE;
    float* out = (float*)d_out;

    int NB = (n + BINSZ - 1) >> BINSHIFT;

    // ws layout: binned[nE] | counts[512] | offsets[513] | cursors[512] | h1[n]
    size_t sz_binned = ((size_t)nE * 4 + 255) & ~(size_t)255;
    size_t sz_meta   = ((size_t)(MAXNB * 2 + MAXNB + 1) * 4 + 255) & ~(size_t)255;
    size_t sz_h1     = ((size_t)n * 4 + 255) & ~(size_t)255;
    size_t need      = sz_binned + sz_meta + sz_h1;

    bool can_bin = (n <= (1 << 20)) && (NB <= MAXNB) && (ws_size >= need);

    if (can_bin) {
        unsigned int* binned = (unsigned int*)d_ws;
        int* counts  = (int*)((char*)d_ws + sz_binned);
        int* offsets = counts + MAXNB;
        int* cursors = offsets + MAXNB + 1;
        float* h1    = (float*)((char*)d_ws + sz_binned + sz_meta);

        hipMemsetAsync(counts, 0, MAXNB * sizeof(int), stream);

        dim3 blk256(256), blk512(512);
        count_bins<<<2048, blk256, 0, stream>>>(dst, nE, NB, counts);
        scan_bins<<<1, MAXNB, 0, stream>>>(counts, offsets, cursors, NB);
        int nChunks = (nE + SCHUNK - 1) / SCHUNK;
        scatter_staged<<<nChunks, blk512, 0, stream>>>(src, dst, nE, NB, cursors, binned);

        reduce_bins<0><<<NB, blk512, 0, stream>>>(binned, offsets, x, w + 0, bias, h1, n);
        reduce_bins<1><<<NB, blk512, 0, stream>>>(binned, offsets, h1, w + 1, bias, out, n);
    } else {
        float* agg1 = (float*)d_ws;
        hipMemsetAsync(agg1, 0, (size_t)n * sizeof(float), stream);
        hipMemsetAsync(out,  0, (size_t)n * sizeof(float), stream);
        int nE4 = nE / 4;
        dim3 blk(256);
        int eblocks = (nE4 + 255) / 256; if (eblocks > 4096) eblocks = 4096;
        int n4 = n / 4;
        int nblocks = (n4 + 255) / 256; if (nblocks > 2048) nblocks = 2048;
        scatter_add4<<<eblocks, blk, 0, stream>>>(x, src, dst, agg1, nE4, nE);
        relu_scale4<<<nblocks, blk, 0, stream>>>(agg1, w + 0, n4);
        scatter_add4<<<eblocks, blk, 0, stream>>>(agg1, src, dst, out, nE4, nE);
        finish4<<<nblocks, blk, 0, stream>>>(out, w + 1, bias, n4);
    }
}